// Round 7
// baseline (7221.371 us; speedup 1.0000x reference)
//
#include <hip/hip_runtime.h>
#include <math.h>

#define EOS_TOK 1
#define SOS_TOK 2

#define Bn 32
#define Hn 512
#define En 256
#define Vn 32000
#define G3H 1536                 // 3*H
#define NROWS (Vn + G3H)         // 33536 = 65.5 * 512
#define NBLK 512                 // 2 blocks/CU (64KB LDS each; 128KB <= 160KB pool)
#define NTHR 1024                // 2x16 waves/CU -> 8 waves/SIMD (occupancy max)
#define GROUPS 32                // row groups of 32 lanes (batch)
#define VT 2                     // rows per thread per pass; 32*2=64 rows/pass
#define GHPB (G3H / NBLK)        // 3 gh rows per block in the pre-pass

typedef unsigned long long ull;

// ---- relaxed agent-scope (device-coherent, no cache-maintenance) accessors ----
template <typename T>
__device__ __forceinline__ T ldA(const T* p) {
    return __hip_atomic_load(p, __ATOMIC_RELAXED, __HIP_MEMORY_SCOPE_AGENT);
}
template <typename T>
__device__ __forceinline__ void stA(T* p, T v) {
    __hip_atomic_store(p, v, __ATOMIC_RELAXED, __HIP_MEMORY_SCOPE_AGENT);
}

// ---- fence-free grid barrier: 32 leaf counters (16 blocks each) + release word ----
struct PadCnt { ull v; ull pad[7]; };
__device__ PadCnt g_leaf[32];     // zero-initialized at module load; monotonic
__device__ ull    g_release;

__device__ __forceinline__ void grid_barrier(int bid) {
    __syncthreads();
    if (threadIdx.x == 0) {
        __builtin_amdgcn_s_waitcnt(0);   // drain my stores/atomics to coherence point
        ull my = __hip_atomic_fetch_add(&g_leaf[bid >> 4].v, 1ull,
                                        __ATOMIC_RELAXED, __HIP_MEMORY_SCOPE_AGENT) + 1;
        ull k = (my + 15) >> 4;          // barrier generation
        if (bid == 0) {
            ull need = k << 4;
            for (;;) {
                bool again = false;
                #pragma unroll
                for (int i = 0; i < 32; ++i)
                    again |= (ldA(&g_leaf[i].v) < need);
                if (!again) break;
                __builtin_amdgcn_s_sleep(1);
            }
            stA(&g_release, k);
        } else {
            while (ldA(&g_release) < k) __builtin_amdgcn_s_sleep(2);
        }
        __asm__ __volatile__("" ::: "memory");
    }
    __syncthreads();
}

// 64 KB exactly.
union SMem {
    float4 h[Bn * (Hn / 4)];                  // 4096 float4, XOR-swizzled
    ull red[GROUPS * Bn];                     // 8 KB, aliases h AFTER all h reads
    struct { int tok[Bn]; float gx[3][Bn]; } a;
};

__device__ __forceinline__ unsigned int fkey(float f) {
    unsigned int b = __float_as_uint(f);
    return (b & 0x80000000u) ? ~b : (b | 0x80000000u);
}

__device__ __forceinline__ const float4* rowp(
    int r, const float* __restrict__ W_proj, const float* __restrict__ W_hh) {
    return (const float4*)((r < Vn) ? (W_proj + (size_t)r * Hn)
                                    : (W_hh   + (size_t)(r - Vn) * Hn));
}

// ---------------- Phase B: logits + next-step gh, partial argmax --------------------
__device__ __forceinline__ void phase_b(
    int tid, int bid, int first, int t,
    const float* __restrict__ W_proj, const float* __restrict__ W_hh,
    const float* __restrict__ b_proj, const float* __restrict__ b_hh,
    const float* __restrict__ ws_h, float* __restrict__ ws_gh,
    ull* __restrict__ slots, SMem* sm)
{
    // stage h (B x H) into swizzled LDS (h was agent-written by phase A)
    const ull* hsrc = (const ull*)ws_h;
    ull* hdst = (ull*)sm->h;
    for (int j = tid; j < Bn * (Hn / 2); j += NTHR) {   // 8192 ull
        int f4 = j >> 1;
        int b  = f4 >> 7;
        int e4 = f4 & 127;
        hdst[((((b << 7) + (e4 ^ (b & 7)))) << 1) | (j & 1)] = ldA(hsrc + j);
    }
    __syncthreads();

    int rs, re;
    if (first) { rs = Vn + bid * GHPB; re = rs + GHPB; }
    else {
        rs = (int)(((long)bid * NROWS) / NBLK);
        re = (int)(((long)(bid + 1) * NROWS) / NBLK);
    }

    const int g  = tid >> 5;        // row group 0..31
    const int b  = tid & 31;        // batch lane
    const int sw = b & 7;
    const float4* hrow = sm->h + (b << 7);
    ull bestPack = 0ull;

    for (int r0 = rs + g * VT; r0 < re; r0 += GROUPS * VT) {
        int r1 = (r0 + 1 < re) ? (r0 + 1) : r0;       // dup row on tail; result unused
        const float4* w0 = rowp(r0, W_proj, W_hh);
        const float4* w1 = rowp(r1, W_proj, W_hh);

        float ax0 = 0.f, ay0 = 0.f, ax1 = 0.f, ay1 = 0.f;
        #pragma unroll 4
        for (int e4 = 0; e4 < Hn / 4; ++e4) {
            float4 h4 = hrow[e4 ^ sw];
            float4 a4 = w0[e4];
            float4 c4 = w1[e4];
            ax0 = fmaf(h4.x, a4.x, ax0);
            ay0 = fmaf(h4.y, a4.y, ay0);
            ax0 = fmaf(h4.z, a4.z, ax0);
            ay0 = fmaf(h4.w, a4.w, ay0);
            ax1 = fmaf(h4.x, c4.x, ax1);
            ay1 = fmaf(h4.y, c4.y, ay1);
            ax1 = fmaf(h4.z, c4.z, ax1);
            ay1 = fmaf(h4.w, c4.w, ay1);
        }
        #pragma unroll
        for (int i = 0; i < VT; ++i) {
            if (r0 + i < re) {
                int r = r0 + i;
                float v = (i == 0) ? (ax0 + ay0) : (ax1 + ay1);
                if (r < Vn) {
                    v += b_proj[r];
                    ull pk = ((ull)fkey(v) << 32) | (unsigned int)(~(unsigned int)r);
                    if (pk > bestPack) bestPack = pk;   // ties: smaller r wins via ~r
                } else {
                    stA(&ws_gh[(size_t)b * G3H + (r - Vn)], v + b_hh[r - Vn]);
                }
            }
        }
    }

    if (!first) {
        __syncthreads();                       // all h reads complete before aliasing
        sm->red[(g << 5) + b] = bestPack;
        __syncthreads();
        if (tid < Bn) {
            ull m = sm->red[tid];
            #pragma unroll
            for (int s = 1; s < GROUPS; ++s) {
                ull v = sm->red[(s << 5) + tid];
                if (v > m) m = v;
            }
            if (m != 0ull)
                atomicMax(&slots[((size_t)(t & 1) * 8 + (bid & 7)) * Bn + tid], m);
        }
    }
}

// ---------------- Phase A: token resolve + embed/gx + gate combine + h update -------
__device__ __forceinline__ void phase_a(
    int tid, int bid, int t, int T,
    const float* __restrict__ emb, const float* __restrict__ W_ih,
    const float* __restrict__ b_ih,
    float* __restrict__ ws_h, float* __restrict__ ws_gh,
    ull* __restrict__ slots, int* __restrict__ done,
    int* __restrict__ out, SMem* sm)
{
    if (tid < Bn) {
        int b = tid;
        int tok, dnew;
        if (t == 0) { tok = SOS_TOK; dnew = 0; }
        else {
            const ull* sl = slots + (size_t)((t - 1) & 1) * (8 * Bn);
            ull m = ldA(&sl[b]);
            #pragma unroll
            for (int s = 1; s < 8; ++s) {
                ull v = ldA(&sl[s * Bn + b]);
                if (v > m) m = v;
            }
            int idx = (int)(~(unsigned int)m);
            int dold = ldA(&done[((t - 1) & 1) * Bn + b]);
            tok  = dold ? EOS_TOK : idx;
            dnew = dold | (idx == EOS_TOK);
        }
        sm->a.tok[b] = tok;
        if (bid == 0) {
            stA(&done[(t & 1) * Bn + b], dnew);
            if (t > 0) out[(size_t)(t - 1) * Bn + b] = tok;
            ull* sr = slots + (size_t)(t & 1) * (8 * Bn);
            #pragma unroll
            for (int s = 0; s < 8; ++s) stA(&sr[s * Bn + b], 0ull);
        }
    }
    __syncthreads();
    if (t >= T) return;          // tail call: resolve only (uniform branch)

    // gx dots: block bid owns column bid; 96 dots (3 gates x 32 b) of length E,
    // 8 threads per dot (32 elems each) -> 768 active threads.
    if (tid < 768) {
        int o    = tid & 7;      // octant of K
        int d    = tid >> 3;     // dot id 0..95
        int b    = d & 31;
        int gate = d >> 5;       // 0..2
        const float* wrow = W_ih + (size_t)(gate * Hn + bid) * En + o * 32;
        const float* xrow = emb + (size_t)sm->a.tok[b] * En + o * 32;
        float ax = 0.f, ay = 0.f;
        #pragma unroll
        for (int e4 = 0; e4 < 8; ++e4) {
            float4 w4 = *(const float4*)(wrow + 4 * e4);
            float4 x4 = *(const float4*)(xrow + 4 * e4);
            ax = fmaf(x4.x, w4.x, ax);
            ay = fmaf(x4.y, w4.y, ay);
            ax = fmaf(x4.z, w4.z, ax);
            ay = fmaf(x4.w, w4.w, ay);
        }
        float a = ax + ay;
        a += __shfl_xor(a, 1);
        a += __shfl_xor(a, 2);
        a += __shfl_xor(a, 4);
        if (o == 0) sm->a.gx[gate][b] = a;
    }
    __syncthreads();

    if (tid < Bn) {
        int b = tid;
        float gxr = sm->a.gx[0][b] + b_ih[bid];
        float gxz = sm->a.gx[1][b] + b_ih[Hn + bid];
        float gxn = sm->a.gx[2][b] + b_ih[2 * Hn + bid];
        float* ghrow = ws_gh + (size_t)b * G3H;            // includes b_hh already
        float ghr = ldA(&ghrow[bid]);
        float ghz = ldA(&ghrow[Hn + bid]);
        float ghn = ldA(&ghrow[2 * Hn + bid]);
        float r = 1.0f / (1.0f + expf(-(gxr + ghr)));
        float z = 1.0f / (1.0f + expf(-(gxz + ghz)));
        float n = tanhf(gxn + r * ghn);
        float* hp = ws_h + (size_t)b * Hn + bid;
        float hold = ldA(hp);
        stA(hp, (1.0f - z) * n + z * hold);
    }
}

// ================= cooperative single-kernel path =================
__global__ void __launch_bounds__(NTHR, 8)
decode_coop(const float* __restrict__ hidden, const float* __restrict__ emb,
            const float* __restrict__ W_ih, const float* __restrict__ W_hh,
            const float* __restrict__ b_ih, const float* __restrict__ b_hh,
            const float* __restrict__ W_proj, const float* __restrict__ b_proj,
            const int* __restrict__ max_len_p, int* __restrict__ out, void* ws_raw)
{
    const int tid = threadIdx.x, bid = blockIdx.x;
    __shared__ SMem sm;

    float* ws_h  = (float*)ws_raw;
    float* ws_gh = ws_h + Bn * Hn;
    ull*   slots = (ull*)(ws_gh + Bn * G3H);
    int*   done  = (int*)(slots + 2 * 8 * Bn);

    const int T = max_len_p[0];

    for (int i = bid * NTHR + tid; i < Bn * Hn / 2; i += NBLK * NTHR)
        stA(((ull*)ws_h) + i, ((const ull*)hidden)[i]);
    grid_barrier(bid);

    phase_b(tid, bid, 1, 0, W_proj, W_hh, b_proj, b_hh, ws_h, ws_gh, slots, &sm);
    grid_barrier(bid);

    for (int t = 0; t < T; ++t) {
        phase_a(tid, bid, t, T, emb, W_ih, b_ih, ws_h, ws_gh, slots, done, out, &sm);
        grid_barrier(bid);
        phase_b(tid, bid, 0, t, W_proj, W_hh, b_proj, b_hh, ws_h, ws_gh, slots, &sm);
        grid_barrier(bid);
    }
    phase_a(tid, bid, T, T, emb, W_ih, b_ih, ws_h, ws_gh, slots, done, out, &sm);
}

// ================= non-cooperative fallback path =================
__global__ void __launch_bounds__(NTHR)
k_init(const float* __restrict__ hidden, float* __restrict__ ws_h) {
    int i = blockIdx.x * NTHR + threadIdx.x;
    if (i < Bn * Hn / 4) ((float4*)ws_h)[i] = ((const float4*)hidden)[i];
}

__global__ void __launch_bounds__(NTHR, 8)
k_b(int first, int t, const int* __restrict__ max_len_p,
    const float* __restrict__ W_proj, const float* __restrict__ W_hh,
    const float* __restrict__ b_proj, const float* __restrict__ b_hh,
    const float* __restrict__ ws_h, float* __restrict__ ws_gh,
    ull* __restrict__ slots)
{
    if (!first && t >= max_len_p[0]) return;
    __shared__ SMem sm;
    phase_b(threadIdx.x, blockIdx.x, first, t, W_proj, W_hh, b_proj, b_hh,
            (const float*)ws_h, ws_gh, slots, &sm);
}

__global__ void __launch_bounds__(NTHR, 8)
k_a(int t, const int* __restrict__ max_len_p,
    const float* __restrict__ emb, const float* __restrict__ W_ih,
    const float* __restrict__ b_ih,
    float* __restrict__ ws_h, float* __restrict__ ws_gh,
    ull* __restrict__ slots, int* __restrict__ done, int* __restrict__ out)
{
    int T = max_len_p[0];
    if (t > T) return;
    __shared__ SMem sm;
    phase_a(threadIdx.x, blockIdx.x, t, T, emb, W_ih, b_ih,
            ws_h, ws_gh, slots, done, out, &sm);
}

extern "C" void kernel_launch(void* const* d_in, const int* in_sizes, int n_in,
                              void* d_out, int out_size, void* d_ws, size_t ws_size,
                              hipStream_t stream) {
    const float* hidden = (const float*)d_in[0];
    const float* emb    = (const float*)d_in[1];
    const float* W_ih   = (const float*)d_in[2];
    const float* W_hh   = (const float*)d_in[3];
    const float* b_ih   = (const float*)d_in[4];
    const float* b_hh   = (const float*)d_in[5];
    const float* W_proj = (const float*)d_in[6];
    const float* b_proj = (const float*)d_in[7];
    const int* max_len  = (const int*)d_in[8];
    int* out = (int*)d_out;

    float* ws_h  = (float*)d_ws;
    float* ws_gh = ws_h + Bn * Hn;
    ull*   slots = (ull*)(ws_gh + Bn * G3H);
    int*   done  = (int*)(slots + 2 * 8 * Bn);
    void*  ws    = d_ws;

    void* args[] = {&hidden, &emb, &W_ih, &W_hh, &b_ih, &b_hh,
                    &W_proj, &b_proj, &max_len, &out, &ws};
    hipError_t err = hipLaunchCooperativeKernel((const void*)decode_coop,
                                                dim3(NBLK), dim3(NTHR), args, 0, stream);
    if (err != hipSuccess) {
        (void)hipGetLastError();   // clear sticky error; deterministic fallback
        hipLaunchKernelGGL(k_init, dim3(4), dim3(NTHR), 0, stream, hidden, ws_h);
        hipLaunchKernelGGL(k_b, dim3(NBLK), dim3(NTHR), 0, stream,
                           1, 0, max_len, W_proj, W_hh, b_proj, b_hh, ws_h, ws_gh, slots);
        for (int t = 0; t <= 64; ++t) {
            hipLaunchKernelGGL(k_a, dim3(NBLK), dim3(NTHR), 0, stream,
                               t, max_len, emb, W_ih, b_ih, ws_h, ws_gh, slots, done, out);
            if (t < 64)
                hipLaunchKernelGGL(k_b, dim3(NBLK), dim3(NTHR), 0, stream,
                                   0, t, max_len, W_proj, W_hh, b_proj, b_hh, ws_h, ws_gh, slots);
        }
    }
}